// Round 2
// baseline (50102.905 us; speedup 1.0000x reference)
//
#include <hip/hip_runtime.h>

#define B_   64
#define T_   512
#define E_   512
#define H_   1024
#define Z_   128
#define G4_  4096   // 4*H
#define WLD_ 1536   // E + H (W1 leading dim)
#define NWG_ 256
#define TC_  128    // time chunk (ws budget: gates chunk 134MB + field chunk 34MB)
#define NCH_ (T_ / TC_)

__device__ __forceinline__ float sigm_(float x) { return 1.f / (1.f + expf(-x)); }
__device__ __forceinline__ float tanh_(float x) {
  float ax = fabsf(x);
  float e  = expf(-2.f * ax);
  float t  = (1.f - e) / (1.f + e);
  return copysignf(t, x);
}

// ---------------------------------------------------------------------------
// Kernel A: gates_d[lt][g][b] = sum_e input_d[b][t0+lt][e] * W1[g][e] + b1[g]
// grid = TC_*32, block = 256. Tile: 128 g x 64 b, BK=16, per-thread 8x4.
// ---------------------------------------------------------------------------
__global__ __launch_bounds__(256) void k_gates_d(const float* __restrict__ xd,
                                                 const float* __restrict__ W1,
                                                 const float* __restrict__ b1,
                                                 float* __restrict__ gd, int t0) {
  __shared__ float As[16][132];  // [k][g] transposed, padded
  __shared__ float Bs[16][68];   // [k][b]
  const int lt  = blockIdx.x >> 5;
  const int tg  = t0 + lt;
  const int g0  = (blockIdx.x & 31) << 7;
  const int tid = threadIdx.x;
  const int tx  = tid & 15;   // b quad
  const int ty  = tid >> 4;   // g oct
  float acc[8][4];
#pragma unroll
  for (int i = 0; i < 8; ++i)
#pragma unroll
    for (int j = 0; j < 4; ++j) acc[i][j] = 0.f;

  const int lg  = tid >> 1;          // 0..127
  const int lk  = (tid & 1) << 3;    // 0/8
  const int lb  = tid >> 2;          // 0..63
  const int lbk = (tid & 3) << 2;    // 0,4,8,12

  for (int k0 = 0; k0 < E_; k0 += 16) {
    float4 w0 = *(const float4*)&W1[(size_t)(g0 + lg) * WLD_ + (k0 + lk)];
    float4 w1 = *(const float4*)&W1[(size_t)(g0 + lg) * WLD_ + (k0 + lk + 4)];
    float4 xv = *(const float4*)&xd[(size_t)lb * (T_ * E_) + (size_t)tg * E_ + (k0 + lbk)];
    As[lk + 0][lg] = w0.x; As[lk + 1][lg] = w0.y; As[lk + 2][lg] = w0.z; As[lk + 3][lg] = w0.w;
    As[lk + 4][lg] = w1.x; As[lk + 5][lg] = w1.y; As[lk + 6][lg] = w1.z; As[lk + 7][lg] = w1.w;
    Bs[lbk + 0][lb] = xv.x; Bs[lbk + 1][lb] = xv.y; Bs[lbk + 2][lb] = xv.z; Bs[lbk + 3][lb] = xv.w;
    __syncthreads();
#pragma unroll
    for (int k = 0; k < 16; ++k) {
      float4 a0 = *(const float4*)&As[k][ty << 3];
      float4 a1 = *(const float4*)&As[k][(ty << 3) + 4];
      float4 bv = *(const float4*)&Bs[k][tx << 2];
      float av[8] = {a0.x, a0.y, a0.z, a0.w, a1.x, a1.y, a1.z, a1.w};
#pragma unroll
      for (int i = 0; i < 8; ++i) {
        acc[i][0] = fmaf(av[i], bv.x, acc[i][0]);
        acc[i][1] = fmaf(av[i], bv.y, acc[i][1]);
        acc[i][2] = fmaf(av[i], bv.z, acc[i][2]);
        acc[i][3] = fmaf(av[i], bv.w, acc[i][3]);
      }
    }
    __syncthreads();
  }
#pragma unroll
  for (int i = 0; i < 8; ++i) {
    const int g = g0 + (ty << 3) + i;
    const float bias = b1[g];
    float4 st = make_float4(acc[i][0] + bias, acc[i][1] + bias,
                            acc[i][2] + bias, acc[i][3] + bias);
    *(float4*)&gd[((size_t)lt * G4_ + g) * B_ + (tx << 2)] = st;
  }
}

// ---------------------------------------------------------------------------
// Kernel B: field[lt][n][b] = sigmoid(lg)*tanh(zh) from input_z @ Wz^T + bz
// grid = TC_*16, block = 256. Tile 64 n x 64 b, BK=32, per-thread 4x4 (x2).
// ---------------------------------------------------------------------------
__global__ __launch_bounds__(256) void k_field(const float* __restrict__ xz,
                                               const float* __restrict__ Wz,
                                               const float* __restrict__ bz,
                                               float* __restrict__ field, int t0) {
  __shared__ float Ls[32][68];
  __shared__ float Zs[32][68];
  __shared__ float Xs[32][68];
  const int lt  = blockIdx.x >> 4;
  const int tg  = t0 + lt;
  const int n0  = (blockIdx.x & 15) << 6;
  const int tid = threadIdx.x;
  const int tx  = tid & 15;
  const int ty  = tid >> 4;
  float aL[4][4], aZ[4][4];
#pragma unroll
  for (int i = 0; i < 4; ++i)
#pragma unroll
    for (int j = 0; j < 4; ++j) { aL[i][j] = 0.f; aZ[i][j] = 0.f; }

  const int ln = tid >> 2;         // 0..63 (row: n or b)
  const int lk = (tid & 3) << 3;   // 0,8,16,24

  for (int k0 = 0; k0 < Z_; k0 += 32) {
    float4 l0 = *(const float4*)&Wz[(size_t)(n0 + ln) * Z_ + k0 + lk];
    float4 l1 = *(const float4*)&Wz[(size_t)(n0 + ln) * Z_ + k0 + lk + 4];
    float4 z0 = *(const float4*)&Wz[(size_t)(H_ + n0 + ln) * Z_ + k0 + lk];
    float4 z1 = *(const float4*)&Wz[(size_t)(H_ + n0 + ln) * Z_ + k0 + lk + 4];
    float4 x0 = *(const float4*)&xz[(size_t)ln * (T_ * Z_) + (size_t)tg * Z_ + k0 + lk];
    float4 x1 = *(const float4*)&xz[(size_t)ln * (T_ * Z_) + (size_t)tg * Z_ + k0 + lk + 4];
    Ls[lk + 0][ln] = l0.x; Ls[lk + 1][ln] = l0.y; Ls[lk + 2][ln] = l0.z; Ls[lk + 3][ln] = l0.w;
    Ls[lk + 4][ln] = l1.x; Ls[lk + 5][ln] = l1.y; Ls[lk + 6][ln] = l1.z; Ls[lk + 7][ln] = l1.w;
    Zs[lk + 0][ln] = z0.x; Zs[lk + 1][ln] = z0.y; Zs[lk + 2][ln] = z0.z; Zs[lk + 3][ln] = z0.w;
    Zs[lk + 4][ln] = z1.x; Zs[lk + 5][ln] = z1.y; Zs[lk + 6][ln] = z1.z; Zs[lk + 7][ln] = z1.w;
    Xs[lk + 0][ln] = x0.x; Xs[lk + 1][ln] = x0.y; Xs[lk + 2][ln] = x0.z; Xs[lk + 3][ln] = x0.w;
    Xs[lk + 4][ln] = x1.x; Xs[lk + 5][ln] = x1.y; Xs[lk + 6][ln] = x1.z; Xs[lk + 7][ln] = x1.w;
    __syncthreads();
#pragma unroll
    for (int k = 0; k < 32; ++k) {
      float4 lv = *(const float4*)&Ls[k][ty << 2];
      float4 zv = *(const float4*)&Zs[k][ty << 2];
      float4 xv = *(const float4*)&Xs[k][tx << 2];
      float lvv[4] = {lv.x, lv.y, lv.z, lv.w};
      float zvv[4] = {zv.x, zv.y, zv.z, zv.w};
      float xvv[4] = {xv.x, xv.y, xv.z, xv.w};
#pragma unroll
      for (int i = 0; i < 4; ++i)
#pragma unroll
        for (int j = 0; j < 4; ++j) {
          aL[i][j] = fmaf(lvv[i], xvv[j], aL[i][j]);
          aZ[i][j] = fmaf(zvv[i], xvv[j], aZ[i][j]);
        }
    }
    __syncthreads();
  }
#pragma unroll
  for (int i = 0; i < 4; ++i) {
    const int nn = n0 + (ty << 2) + i;
    const float bL = bz[nn];
    const float bZ = bz[H_ + nn];
    float4 o;
    o.x = sigm_(aL[i][0] + bL) * tanh_(aZ[i][0] + bZ);
    o.y = sigm_(aL[i][1] + bL) * tanh_(aZ[i][1] + bZ);
    o.z = sigm_(aL[i][2] + bL) * tanh_(aZ[i][2] + bZ);
    o.w = sigm_(aL[i][3] + bL) * tanh_(aZ[i][3] + bZ);
    *(float4*)&field[((size_t)lt * H_ + nn) * B_ + (tx << 2)] = o;
  }
}

// ---------------------------------------------------------------------------
// Grid barrier: flat atomic counter + generation flag (device scope).
// ---------------------------------------------------------------------------
__device__ __forceinline__ void grid_barrier(unsigned* bar) {
  __syncthreads();
  if (threadIdx.x == 0) {
    unsigned gen = __hip_atomic_load(&bar[1], __ATOMIC_RELAXED, __HIP_MEMORY_SCOPE_AGENT);
    __threadfence();  // release this WG's h writes
    unsigned old = __hip_atomic_fetch_add(&bar[0], 1u, __ATOMIC_ACQ_REL, __HIP_MEMORY_SCOPE_AGENT);
    if (old == NWG_ - 1) {
      __hip_atomic_store(&bar[0], 0u, __ATOMIC_RELAXED, __HIP_MEMORY_SCOPE_AGENT);
      __hip_atomic_fetch_add(&bar[1], 1u, __ATOMIC_RELEASE, __HIP_MEMORY_SCOPE_AGENT);
    } else {
      while (__hip_atomic_load(&bar[1], __ATOMIC_ACQUIRE, __HIP_MEMORY_SCOPE_AGENT) == gen) {
        __builtin_amdgcn_s_sleep(8);
      }
    }
    __threadfence();  // acquire other WGs' h writes (invalidates this CU's L1)
  }
  __syncthreads();
}

// ---------------------------------------------------------------------------
// Kernel C: persistent scan over TC_ steps. 256 WGs (1/CU) x 512 threads.
// WG wg owns 4 h-columns n0..n0+3; their 16 Wh rows (K=1024) live in 64KB LDS
// as lw[k][gate*4+col]. Thread (b = tid&63, s = tid>>6): s = K-slice of 128;
// each thread computes ALL 16 (gate,col) partials for its slice -> each h
// element is read exactly once per CU per step (min traffic). Waves s>=1
// push partials via relaxed device-scope atomics; wave 0 reduces, does the
// cell update, writes h (transposed [k][b] double buffer) and the output.
// ---------------------------------------------------------------------------
__global__ __launch_bounds__(512, 2) void k_rnn(const float* __restrict__ gd,
                                                const float* __restrict__ field,
                                                const float* __restrict__ hidden,
                                                const float* __restrict__ W1,
                                                float* __restrict__ out,
                                                float* __restrict__ h0b,
                                                float* __restrict__ h1b,
                                                float* __restrict__ cbuf,
                                                float* __restrict__ xch,
                                                unsigned* __restrict__ bar, int t0) {
  __shared__ float lw[16 * 1024];  // 64KB: lw[k*16 + gate*4 + col]
  const int wg  = blockIdx.x;
  const int tid = threadIdx.x;
  const int b   = tid & 63;
  const int s   = tid >> 6;       // wave id == K-slice (wave-uniform)
  const int n0  = wg << 2;

  // Stage lw[k][gt*4+q] = W1[gt*1024 + n0 + q][E_ + k], k = 0..1023.
  {
    const int r  = tid >> 5;        // 0..15 -> (gt,q) row
    const int gt = r >> 2, qq = r & 3;
    const float* src = &W1[(size_t)((gt << 10) + n0 + qq) * WLD_ + E_];
    const int kb = (tid & 31) << 5; // 32-float chunk of K
#pragma unroll
    for (int i = 0; i < 8; ++i) {
      const int k = kb + (i << 2);
      float4 v = *(const float4*)&src[k];
      lw[((k + 0) << 4) + r] = v.x;
      lw[((k + 1) << 4) + r] = v.y;
      lw[((k + 2) << 4) + r] = v.z;
      lw[((k + 3) << 4) + r] = v.w;
    }
  }

  float cr[4] = {0.f, 0.f, 0.f, 0.f};
  float hr[4] = {0.f, 0.f, 0.f, 0.f};
  if (s == 0) {
    if (t0 == 0) {
      float4 hv4 = *(const float4*)&hidden[(size_t)b * (2 * H_) + n0];
      float4 cv4 = *(const float4*)&hidden[(size_t)b * (2 * H_) + H_ + n0];
      hr[0] = hv4.x; hr[1] = hv4.y; hr[2] = hv4.z; hr[3] = hv4.w;
      cr[0] = cv4.x; cr[1] = cv4.y; cr[2] = cv4.z; cr[3] = cv4.w;
      h0b[((n0 + 0) << 6) + b] = hr[0];
      h0b[((n0 + 1) << 6) + b] = hr[1];
      h0b[((n0 + 2) << 6) + b] = hr[2];
      h0b[((n0 + 3) << 6) + b] = hr[3];
    } else {
      float4 cv4 = *(const float4*)&cbuf[((size_t)b << 10) + n0];
      cr[0] = cv4.x; cr[1] = cv4.y; cr[2] = cv4.z; cr[3] = cv4.w;
      // h0b persists from the previous chunk launch (TC_ even -> ends in h0b)
    }
  }
  grid_barrier(bar);  // h0b + lw visible

  float* hcur = h0b;
  float* hnxt = h1b;
  const float* wp = lw + (s << 11);                 // k0 = s*128 -> *16 floats
  float* xw = xch + (((wg << 3) + s) << 10) + b;    // [wg][s][r][b]

  for (int lt = 0; lt < TC_; ++lt) {
    float gdl[4][4];
    float fldq[4];
    if (s == 0) {  // issue early; latency hides under the K-loop
      const size_t gb = ((size_t)lt * G4_ + n0) * B_ + b;
#pragma unroll
      for (int gt = 0; gt < 4; ++gt)
#pragma unroll
        for (int q = 0; q < 4; ++q)
          gdl[gt][q] = gd[gb + ((size_t)gt << 16) + (q << 6)];
#pragma unroll
      for (int q = 0; q < 4; ++q)
        fldq[q] = field[((size_t)lt * H_ + n0 + q) * B_ + b];
    }

    float acc[16];
#pragma unroll
    for (int r = 0; r < 16; ++r) acc[r] = 0.f;
    const float* hp = hcur + (s << 13) + b;  // h[k][b], k = s*128 + i
#pragma unroll 4
    for (int i = 0; i < 128; ++i) {
      const float hvv = hp[i << 6];
      const float* w = wp + (i << 4);
      const float4 w0 = *(const float4*)(w);       // gate i, cols 0..3
      const float4 w1 = *(const float4*)(w + 4);   // gate f
      const float4 w2 = *(const float4*)(w + 8);   // gate g
      const float4 w3 = *(const float4*)(w + 12);  // gate o
      acc[0]  = fmaf(hvv, w0.x, acc[0]);
      acc[1]  = fmaf(hvv, w0.y, acc[1]);
      acc[2]  = fmaf(hvv, w0.z, acc[2]);
      acc[3]  = fmaf(hvv, w0.w, acc[3]);
      acc[4]  = fmaf(hvv, w1.x, acc[4]);
      acc[5]  = fmaf(hvv, w1.y, acc[5]);
      acc[6]  = fmaf(hvv, w1.z, acc[6]);
      acc[7]  = fmaf(hvv, w1.w, acc[7]);
      acc[8]  = fmaf(hvv, w2.x, acc[8]);
      acc[9]  = fmaf(hvv, w2.y, acc[9]);
      acc[10] = fmaf(hvv, w2.z, acc[10]);
      acc[11] = fmaf(hvv, w2.w, acc[11]);
      acc[12] = fmaf(hvv, w3.x, acc[12]);
      acc[13] = fmaf(hvv, w3.y, acc[13]);
      acc[14] = fmaf(hvv, w3.z, acc[14]);
      acc[15] = fmaf(hvv, w3.w, acc[15]);
    }

    if (s != 0) {  // push partials (relaxed atomics: L1-bypassing, pipelined)
#pragma unroll
      for (int r = 0; r < 16; ++r)
        __hip_atomic_store(xw + (r << 6), acc[r], __ATOMIC_RELAXED, __HIP_MEMORY_SCOPE_AGENT);
    }
    __syncthreads();  // drains vmcnt -> partials visible CU/agent-wide
    if (s == 0) {
#pragma unroll
      for (int ss = 1; ss < 8; ++ss) {
        const float* xp = xch + (((wg << 3) + ss) << 10) + b;
#pragma unroll
        for (int r = 0; r < 16; ++r)
          acc[r] += __hip_atomic_load(xp + (r << 6), __ATOMIC_RELAXED, __HIP_MEMORY_SCOPE_AGENT);
      }
#pragma unroll
      for (int q = 0; q < 4; ++q) {
        const float gi = acc[q]      + gdl[0][q];
        const float gf = acc[4 + q]  + gdl[1][q];
        const float gg = acc[8 + q]  + gdl[2][q];
        const float go = acc[12 + q] + gdl[3][q];
        float cc = sigm_(gf + 1.f) * cr[q] + sigm_(gi) * tanh_(gg) + fldq[q];
        cr[q] = cc;
        hr[q] = sigm_(go) * tanh_(cc);
      }
      hnxt[((n0 + 0) << 6) + b] = hr[0];
      hnxt[((n0 + 1) << 6) + b] = hr[1];
      hnxt[((n0 + 2) << 6) + b] = hr[2];
      hnxt[((n0 + 3) << 6) + b] = hr[3];
      *(float4*)&out[((size_t)b * T_ + (t0 + lt)) * H_ + n0] =
          make_float4(hr[0], hr[1], hr[2], hr[3]);
    }
    grid_barrier(bar);
    float* tmp = hcur; hcur = hnxt; hnxt = tmp;
  }

  if (s == 0) {
    *(float4*)&cbuf[((size_t)b << 10) + n0] = make_float4(cr[0], cr[1], cr[2], cr[3]);
    if (t0 == T_ - TC_) {
      *(float4*)&out[(size_t)B_ * T_ * H_ + (size_t)b * H_ + n0] =
          make_float4(hr[0], hr[1], hr[2], hr[3]);
      *(float4*)&out[(size_t)B_ * T_ * H_ + (size_t)B_ * H_ + (size_t)b * H_ + n0] =
          make_float4(cr[0], cr[1], cr[2], cr[3]);
    }
  }
}

// ---------------------------------------------------------------------------
extern "C" void kernel_launch(void* const* d_in, const int* in_sizes, int n_in,
                              void* d_out, int out_size, void* d_ws, size_t ws_size,
                              hipStream_t stream) {
  const float* xd     = (const float*)d_in[0];
  const float* xz     = (const float*)d_in[1];
  const float* hidden = (const float*)d_in[2];
  const float* W1     = (const float*)d_in[3];
  const float* b1     = (const float*)d_in[4];
  const float* Wz     = (const float*)d_in[5];
  const float* bz     = (const float*)d_in[6];
  float* out = (float*)d_out;
  float* ws  = (float*)d_ws;

  // ws layout (floats): gd chunk 33554432 | field chunk 8388608 | h0 65536 |
  //   h1 65536 | cbuf 65536 | xch 2097152 | bar (2 u32).  Total ~177 MB.
  float* gd    = ws;
  float* field = gd + (size_t)TC_ * G4_ * B_;
  float* h0b   = field + (size_t)TC_ * H_ * B_;
  float* h1b   = h0b + (size_t)H_ * B_;
  float* cbuf  = h1b + (size_t)H_ * B_;
  float* xch   = cbuf + (size_t)H_ * B_;
  unsigned* bar = (unsigned*)(xch + (size_t)NWG_ * 8 * 16 * 64);

  hipMemsetAsync(bar, 0, 2 * sizeof(unsigned), stream);
  for (int c = 0; c < NCH_; ++c) {
    const int t0 = c * TC_;
    k_gates_d<<<dim3(TC_ * 32), dim3(256), 0, stream>>>(xd, W1, b1, gd, t0);
    k_field<<<dim3(TC_ * 16), dim3(256), 0, stream>>>(xz, Wz, bz, field, t0);
    k_rnn<<<dim3(NWG_), dim3(512), 0, stream>>>(gd, field, hidden, W1, out,
                                                h0b, h1b, cbuf, xch, bar, t0);
  }
}

// Round 3
// 22043.301 us; speedup vs baseline: 2.2729x; 2.2729x over previous
//
#include <hip/hip_runtime.h>

#define B_   64
#define T_   512
#define E_   512
#define H_   1024
#define Z_   128
#define G4_  4096   // 4*H
#define WLD_ 1536   // E + H (W1 leading dim)
#define NWG_ 256
#define TC_  128    // time chunk
#define NCH_ (T_ / TC_)

__device__ __forceinline__ float sigm_(float x) { return 1.f / (1.f + expf(-x)); }
__device__ __forceinline__ float tanh_(float x) {
  float ax = fabsf(x);
  float e  = expf(-2.f * ax);
  float t  = (1.f - e) / (1.f + e);
  return copysignf(t, x);
}

#define LLC_LD(p)     __hip_atomic_load((p), __ATOMIC_RELAXED, __HIP_MEMORY_SCOPE_AGENT)
#define LLC_ST(p, v)  __hip_atomic_store((p), (v), __ATOMIC_RELAXED, __HIP_MEMORY_SCOPE_AGENT)

// ---------------------------------------------------------------------------
// Kernel A: gates_d[lt][g][b] = sum_e input_d[b][t0+lt][e] * W1[g][e] + b1[g]
// ---------------------------------------------------------------------------
__global__ __launch_bounds__(256) void k_gates_d(const float* __restrict__ xd,
                                                 const float* __restrict__ W1,
                                                 const float* __restrict__ b1,
                                                 float* __restrict__ gd, int t0) {
  __shared__ float As[16][132];  // [k][g] transposed, padded
  __shared__ float Bs[16][68];   // [k][b]
  const int lt  = blockIdx.x >> 5;
  const int tg  = t0 + lt;
  const int g0  = (blockIdx.x & 31) << 7;
  const int tid = threadIdx.x;
  const int tx  = tid & 15;   // b quad
  const int ty  = tid >> 4;   // g oct
  float acc[8][4];
#pragma unroll
  for (int i = 0; i < 8; ++i)
#pragma unroll
    for (int j = 0; j < 4; ++j) acc[i][j] = 0.f;

  const int lg  = tid >> 1;          // 0..127
  const int lk  = (tid & 1) << 3;    // 0/8
  const int lb  = tid >> 2;          // 0..63
  const int lbk = (tid & 3) << 2;    // 0,4,8,12

  for (int k0 = 0; k0 < E_; k0 += 16) {
    float4 w0 = *(const float4*)&W1[(size_t)(g0 + lg) * WLD_ + (k0 + lk)];
    float4 w1 = *(const float4*)&W1[(size_t)(g0 + lg) * WLD_ + (k0 + lk + 4)];
    float4 xv = *(const float4*)&xd[(size_t)lb * (T_ * E_) + (size_t)tg * E_ + (k0 + lbk)];
    As[lk + 0][lg] = w0.x; As[lk + 1][lg] = w0.y; As[lk + 2][lg] = w0.z; As[lk + 3][lg] = w0.w;
    As[lk + 4][lg] = w1.x; As[lk + 5][lg] = w1.y; As[lk + 6][lg] = w1.z; As[lk + 7][lg] = w1.w;
    Bs[lbk + 0][lb] = xv.x; Bs[lbk + 1][lb] = xv.y; Bs[lbk + 2][lb] = xv.z; Bs[lbk + 3][lb] = xv.w;
    __syncthreads();
#pragma unroll
    for (int k = 0; k < 16; ++k) {
      float4 a0 = *(const float4*)&As[k][ty << 3];
      float4 a1 = *(const float4*)&As[k][(ty << 3) + 4];
      float4 bv = *(const float4*)&Bs[k][tx << 2];
      float av[8] = {a0.x, a0.y, a0.z, a0.w, a1.x, a1.y, a1.z, a1.w};
#pragma unroll
      for (int i = 0; i < 8; ++i) {
        acc[i][0] = fmaf(av[i], bv.x, acc[i][0]);
        acc[i][1] = fmaf(av[i], bv.y, acc[i][1]);
        acc[i][2] = fmaf(av[i], bv.z, acc[i][2]);
        acc[i][3] = fmaf(av[i], bv.w, acc[i][3]);
      }
    }
    __syncthreads();
  }
#pragma unroll
  for (int i = 0; i < 8; ++i) {
    const int g = g0 + (ty << 3) + i;
    const float bias = b1[g];
    float4 st = make_float4(acc[i][0] + bias, acc[i][1] + bias,
                            acc[i][2] + bias, acc[i][3] + bias);
    *(float4*)&gd[((size_t)lt * G4_ + g) * B_ + (tx << 2)] = st;
  }
}

// ---------------------------------------------------------------------------
// Kernel B: field[lt][n][b] = sigmoid(lg)*tanh(zh) from input_z @ Wz^T + bz
// ---------------------------------------------------------------------------
__global__ __launch_bounds__(256) void k_field(const float* __restrict__ xz,
                                               const float* __restrict__ Wz,
                                               const float* __restrict__ bz,
                                               float* __restrict__ field, int t0) {
  __shared__ float Ls[32][68];
  __shared__ float Zs[32][68];
  __shared__ float Xs[32][68];
  const int lt  = blockIdx.x >> 4;
  const int tg  = t0 + lt;
  const int n0  = (blockIdx.x & 15) << 6;
  const int tid = threadIdx.x;
  const int tx  = tid & 15;
  const int ty  = tid >> 4;
  float aL[4][4], aZ[4][4];
#pragma unroll
  for (int i = 0; i < 4; ++i)
#pragma unroll
    for (int j = 0; j < 4; ++j) { aL[i][j] = 0.f; aZ[i][j] = 0.f; }

  const int ln = tid >> 2;         // 0..63 (row: n or b)
  const int lk = (tid & 3) << 3;   // 0,8,16,24

  for (int k0 = 0; k0 < Z_; k0 += 32) {
    float4 l0 = *(const float4*)&Wz[(size_t)(n0 + ln) * Z_ + k0 + lk];
    float4 l1 = *(const float4*)&Wz[(size_t)(n0 + ln) * Z_ + k0 + lk + 4];
    float4 z0 = *(const float4*)&Wz[(size_t)(H_ + n0 + ln) * Z_ + k0 + lk];
    float4 z1 = *(const float4*)&Wz[(size_t)(H_ + n0 + ln) * Z_ + k0 + lk + 4];
    float4 x0 = *(const float4*)&xz[(size_t)ln * (T_ * Z_) + (size_t)tg * Z_ + k0 + lk];
    float4 x1 = *(const float4*)&xz[(size_t)ln * (T_ * Z_) + (size_t)tg * Z_ + k0 + lk + 4];
    Ls[lk + 0][ln] = l0.x; Ls[lk + 1][ln] = l0.y; Ls[lk + 2][ln] = l0.z; Ls[lk + 3][ln] = l0.w;
    Ls[lk + 4][ln] = l1.x; Ls[lk + 5][ln] = l1.y; Ls[lk + 6][ln] = l1.z; Ls[lk + 7][ln] = l1.w;
    Zs[lk + 0][ln] = z0.x; Zs[lk + 1][ln] = z0.y; Zs[lk + 2][ln] = z0.z; Zs[lk + 3][ln] = z0.w;
    Zs[lk + 4][ln] = z1.x; Zs[lk + 5][ln] = z1.y; Zs[lk + 6][ln] = z1.z; Zs[lk + 7][ln] = z1.w;
    Xs[lk + 0][ln] = x0.x; Xs[lk + 1][ln] = x0.y; Xs[lk + 2][ln] = x0.z; Xs[lk + 3][ln] = x0.w;
    Xs[lk + 4][ln] = x1.x; Xs[lk + 5][ln] = x1.y; Xs[lk + 6][ln] = x1.z; Xs[lk + 7][ln] = x1.w;
    __syncthreads();
#pragma unroll
    for (int k = 0; k < 32; ++k) {
      float4 lv = *(const float4*)&Ls[k][ty << 2];
      float4 zv = *(const float4*)&Zs[k][ty << 2];
      float4 xv = *(const float4*)&Xs[k][tx << 2];
      float lvv[4] = {lv.x, lv.y, lv.z, lv.w};
      float zvv[4] = {zv.x, zv.y, zv.z, zv.w};
      float xvv[4] = {xv.x, xv.y, xv.z, xv.w};
#pragma unroll
      for (int i = 0; i < 4; ++i)
#pragma unroll
        for (int j = 0; j < 4; ++j) {
          aL[i][j] = fmaf(lvv[i], xvv[j], aL[i][j]);
          aZ[i][j] = fmaf(zvv[i], xvv[j], aZ[i][j]);
        }
    }
    __syncthreads();
  }
#pragma unroll
  for (int i = 0; i < 4; ++i) {
    const int nn = n0 + (ty << 2) + i;
    const float bL = bz[nn];
    const float bZ = bz[H_ + nn];
    float4 o;
    o.x = sigm_(aL[i][0] + bL) * tanh_(aZ[i][0] + bZ);
    o.y = sigm_(aL[i][1] + bL) * tanh_(aZ[i][1] + bZ);
    o.z = sigm_(aL[i][2] + bL) * tanh_(aZ[i][2] + bZ);
    o.w = sigm_(aL[i][3] + bL) * tanh_(aZ[i][3] + bZ);
    *(float4*)&field[((size_t)lt * H_ + nn) * B_ + (tx << 2)] = o;
  }
}

// ---------------------------------------------------------------------------
// Fence-free grid barrier: store-slot + aggregator (WG0). All flag traffic is
// LLC-direct relaxed atomics; NO threadfence (no L1/L2 invalidates, no wbl2).
// Visibility: callers __syncthreads() before arriving (drains vmcnt -> all
// prior LLC-direct stores are at LLC); LLC is the single coherence point.
// Caller MUST __syncthreads() immediately before this.
// ---------------------------------------------------------------------------
__device__ __forceinline__ void arrive_wait(unsigned* __restrict__ slots,
                                            unsigned* __restrict__ root,
                                            int wg, int tid, unsigned target) {
  if (tid == 0) LLC_ST(&slots[wg], target);
  if (wg == 0) {
    if (tid < NWG_) {
      while (LLC_LD(&slots[tid]) < target) __builtin_amdgcn_s_sleep(2);
    }
    __syncthreads();
    if (tid == 0) LLC_ST(root, target);
  } else {
    if (tid == 0) {
      while (LLC_LD(root) < target) __builtin_amdgcn_s_sleep(2);
    }
    __syncthreads();
  }
}

// ---------------------------------------------------------------------------
// Kernel C: persistent scan over TC_ steps. 256 WGs (1/CU) x 512 threads.
// WG wg owns 4 h-columns; 16 Wh rows (K=1024) resident in 64KB LDS.
// Thread (b = tid&63, s = tid>>6): s = K-slice of 128, computes all 16
// (gate,col) partials. All cross-WG data (h, partials) via LLC-direct
// relaxed atomics -> no fences anywhere.
// ---------------------------------------------------------------------------
__global__ __launch_bounds__(512, 2) void k_rnn(const float* __restrict__ gd,
                                                const float* __restrict__ field,
                                                const float* __restrict__ hidden,
                                                const float* __restrict__ W1,
                                                float* __restrict__ out,
                                                float* __restrict__ h0b,
                                                float* __restrict__ h1b,
                                                float* __restrict__ cbuf,
                                                float* __restrict__ xch,
                                                unsigned* __restrict__ slots,
                                                unsigned* __restrict__ root,
                                                int t0, unsigned gbase) {
  __shared__ float lw[16 * 1024];  // 64KB: lw[k*16 + gate*4 + col]
  const int wg  = blockIdx.x;
  const int tid = threadIdx.x;
  const int b   = tid & 63;
  const int s   = tid >> 6;       // wave id == K-slice (wave-uniform)
  const int n0  = wg << 2;

  // Stage lw[k][gt*4+q] = W1[gt*1024 + n0 + q][E_ + k], k = 0..1023.
  {
    const int r  = tid >> 5;        // 0..15 -> (gt,q) row
    const int gt = r >> 2, qq = r & 3;
    const float* src = &W1[(size_t)((gt << 10) + n0 + qq) * WLD_ + E_];
    const int kb = (tid & 31) << 5; // 32-float chunk of K
#pragma unroll
    for (int i = 0; i < 8; ++i) {
      const int k = kb + (i << 2);
      float4 v = *(const float4*)&src[k];
      lw[((k + 0) << 4) + r] = v.x;
      lw[((k + 1) << 4) + r] = v.y;
      lw[((k + 2) << 4) + r] = v.z;
      lw[((k + 3) << 4) + r] = v.w;
    }
  }

  float cr[4] = {0.f, 0.f, 0.f, 0.f};
  float hr[4] = {0.f, 0.f, 0.f, 0.f};
  if (s == 0) {
    if (t0 == 0) {
      float4 hv4 = *(const float4*)&hidden[(size_t)b * (2 * H_) + n0];
      float4 cv4 = *(const float4*)&hidden[(size_t)b * (2 * H_) + H_ + n0];
      hr[0] = hv4.x; hr[1] = hv4.y; hr[2] = hv4.z; hr[3] = hv4.w;
      cr[0] = cv4.x; cr[1] = cv4.y; cr[2] = cv4.z; cr[3] = cv4.w;
      LLC_ST(&h0b[((n0 + 0) << 6) + b], hr[0]);
      LLC_ST(&h0b[((n0 + 1) << 6) + b], hr[1]);
      LLC_ST(&h0b[((n0 + 2) << 6) + b], hr[2]);
      LLC_ST(&h0b[((n0 + 3) << 6) + b], hr[3]);
    } else {
      float4 cv4 = *(const float4*)&cbuf[((size_t)b << 10) + n0];
      cr[0] = cv4.x; cr[1] = cv4.y; cr[2] = cv4.z; cr[3] = cv4.w;
      // h0b persists from the previous chunk launch (ends in h0b; atomics->LLC)
    }
  }
  __syncthreads();                       // drain h0b stores + LDS staging
  arrive_wait(slots, root, wg, tid, gbase + 1);

  float* hcur = h0b;
  float* hnxt = h1b;
  const float* wp = lw + (s << 11);                 // k0 = s*128 -> *16 floats
  float* xw = xch + (((wg << 3) + s) << 10) + b;    // [wg][s][r][b]

  for (int lt = 0; lt < TC_; ++lt) {
    float gdl[4][4];
    float fldq[4];
    if (s == 0) {  // issue early; latency hides under the K-loop
      const size_t gb = ((size_t)lt * G4_ + n0) * B_ + b;
#pragma unroll
      for (int gt = 0; gt < 4; ++gt)
#pragma unroll
        for (int q = 0; q < 4; ++q)
          gdl[gt][q] = gd[gb + ((size_t)gt << 16) + (q << 6)];
#pragma unroll
      for (int q = 0; q < 4; ++q)
        fldq[q] = field[((size_t)lt * H_ + n0 + q) * B_ + b];
    }

    float acc[16];
#pragma unroll
    for (int r = 0; r < 16; ++r) acc[r] = 0.f;
    const float* hp = hcur + (s << 13) + b;  // h[k][b], k = s*128 + i
#pragma unroll 2
    for (int ib = 0; ib < 128; ib += 8) {
      float hb8[8];
#pragma unroll
      for (int j = 0; j < 8; ++j)
        hb8[j] = LLC_LD(hp + ((ib + j) << 6));
#pragma unroll
      for (int j = 0; j < 8; ++j) {
        const float* w = wp + ((ib + j) << 4);
        const float4 w0 = *(const float4*)(w);       // gate i, cols 0..3
        const float4 w1 = *(const float4*)(w + 4);   // gate f
        const float4 w2 = *(const float4*)(w + 8);   // gate g
        const float4 w3 = *(const float4*)(w + 12);  // gate o
        const float hvv = hb8[j];
        acc[0]  = fmaf(hvv, w0.x, acc[0]);
        acc[1]  = fmaf(hvv, w0.y, acc[1]);
        acc[2]  = fmaf(hvv, w0.z, acc[2]);
        acc[3]  = fmaf(hvv, w0.w, acc[3]);
        acc[4]  = fmaf(hvv, w1.x, acc[4]);
        acc[5]  = fmaf(hvv, w1.y, acc[5]);
        acc[6]  = fmaf(hvv, w1.z, acc[6]);
        acc[7]  = fmaf(hvv, w1.w, acc[7]);
        acc[8]  = fmaf(hvv, w2.x, acc[8]);
        acc[9]  = fmaf(hvv, w2.y, acc[9]);
        acc[10] = fmaf(hvv, w2.z, acc[10]);
        acc[11] = fmaf(hvv, w2.w, acc[11]);
        acc[12] = fmaf(hvv, w3.x, acc[12]);
        acc[13] = fmaf(hvv, w3.y, acc[13]);
        acc[14] = fmaf(hvv, w3.z, acc[14]);
        acc[15] = fmaf(hvv, w3.w, acc[15]);
      }
    }

    if (s != 0) {  // push partials (LLC-direct, pipelined)
#pragma unroll
      for (int r = 0; r < 16; ++r)
        LLC_ST(xw + (r << 6), acc[r]);
    }
    __syncthreads();  // drains vmcnt -> partials at LLC
    if (s == 0) {
#pragma unroll
      for (int ss = 1; ss < 8; ++ss) {
        const float* xp = xch + (((wg << 3) + ss) << 10) + b;
#pragma unroll
        for (int r = 0; r < 16; ++r)
          acc[r] += LLC_LD(xp + (r << 6));
      }
#pragma unroll
      for (int q = 0; q < 4; ++q) {
        const float gi = acc[q]      + gdl[0][q];
        const float gf = acc[4 + q]  + gdl[1][q];
        const float gg = acc[8 + q]  + gdl[2][q];
        const float go = acc[12 + q] + gdl[3][q];
        float cc = sigm_(gf + 1.f) * cr[q] + sigm_(gi) * tanh_(gg) + fldq[q];
        cr[q] = cc;
        hr[q] = sigm_(go) * tanh_(cc);
      }
      LLC_ST(&hnxt[((n0 + 0) << 6) + b], hr[0]);
      LLC_ST(&hnxt[((n0 + 1) << 6) + b], hr[1]);
      LLC_ST(&hnxt[((n0 + 2) << 6) + b], hr[2]);
      LLC_ST(&hnxt[((n0 + 3) << 6) + b], hr[3]);
      *(float4*)&out[((size_t)b * T_ + (t0 + lt)) * H_ + n0] =
          make_float4(hr[0], hr[1], hr[2], hr[3]);
    }
    __syncthreads();  // drain wave0's h stores (vmcnt(0) before s_barrier)
    arrive_wait(slots, root, wg, tid, gbase + 2 + (unsigned)lt);
    float* tmp = hcur; hcur = hnxt; hnxt = tmp;
  }

  if (s == 0) {
    *(float4*)&cbuf[((size_t)b << 10) + n0] = make_float4(cr[0], cr[1], cr[2], cr[3]);
    if (t0 == T_ - TC_) {
      *(float4*)&out[(size_t)B_ * T_ * H_ + (size_t)b * H_ + n0] =
          make_float4(hr[0], hr[1], hr[2], hr[3]);
      *(float4*)&out[(size_t)B_ * T_ * H_ + (size_t)B_ * H_ + (size_t)b * H_ + n0] =
          make_float4(cr[0], cr[1], cr[2], cr[3]);
    }
  }
}

// ---------------------------------------------------------------------------
extern "C" void kernel_launch(void* const* d_in, const int* in_sizes, int n_in,
                              void* d_out, int out_size, void* d_ws, size_t ws_size,
                              hipStream_t stream) {
  const float* xd     = (const float*)d_in[0];
  const float* xz     = (const float*)d_in[1];
  const float* hidden = (const float*)d_in[2];
  const float* W1     = (const float*)d_in[3];
  const float* b1     = (const float*)d_in[4];
  const float* Wz     = (const float*)d_in[5];
  const float* bz     = (const float*)d_in[6];
  float* out = (float*)d_out;
  float* ws  = (float*)d_ws;

  // ws layout (floats): gd chunk 33554432 | field chunk 8388608 | h0 65536 |
  //   h1 65536 | cbuf 65536 | xch 2097152 | slots[256]+root.  Total ~177 MB.
  float* gd    = ws;
  float* field = gd + (size_t)TC_ * G4_ * B_;
  float* h0b   = field + (size_t)TC_ * H_ * B_;
  float* h1b   = h0b + (size_t)H_ * B_;
  float* cbuf  = h1b + (size_t)H_ * B_;
  float* xch   = cbuf + (size_t)H_ * B_;
  unsigned* slots = (unsigned*)(xch + (size_t)NWG_ * 8 * 16 * 64);
  unsigned* root  = slots + NWG_;  // own cacheline (slots are 1024B)

  hipMemsetAsync(slots, 0, 2048, stream);
  for (int c = 0; c < NCH_; ++c) {
    const int t0 = c * TC_;
    const unsigned gbase = (unsigned)c * (TC_ + 1);
    k_gates_d<<<dim3(TC_ * 32), dim3(256), 0, stream>>>(xd, W1, b1, gd, t0);
    k_field<<<dim3(TC_ * 16), dim3(256), 0, stream>>>(xz, Wz, bz, field, t0);
    k_rnn<<<dim3(NWG_), dim3(512), 0, stream>>>(gd, field, hidden, W1, out,
                                                h0b, h1b, cbuf, xch,
                                                slots, root, t0, gbase);
  }
}

// Round 5
// 4890.530 us; speedup vs baseline: 10.2449x; 4.5073x over previous
//
#include <hip/hip_runtime.h>
#include <hip/hip_bf16.h>

#define B_   64
#define T_   512
#define E_   512
#define H_   1024
#define Z_   128
#define G4_  4096   // 4*H
#define WLD_ 1536   // E + H (W1 leading dim)
#define NWG_ 256
#define TC_  128    // time chunk
#define NCH_ (T_ / TC_)

typedef unsigned short ushort_t;
typedef unsigned long long ull_t;
using f32x4  = __attribute__((ext_vector_type(4))) float;
using bf16x8 = __attribute__((ext_vector_type(8))) short;

__device__ __forceinline__ float sigm_(float x) { return 1.f / (1.f + expf(-x)); }
__device__ __forceinline__ float tanh_(float x) {
  float ax = fabsf(x);
  float e  = expf(-2.f * ax);
  float t  = (1.f - e) / (1.f + e);
  return copysignf(t, x);
}
__device__ __forceinline__ ushort_t f2bf(float x) {
  __hip_bfloat16 h = __float2bfloat16(x);
  ushort_t u; __builtin_memcpy(&u, &h, 2); return u;
}
__device__ __forceinline__ float bf2f(ushort_t u) {
  __hip_bfloat16 h; __builtin_memcpy(&h, &u, 2); return __bfloat162float(h);
}

#define LLC_LD(p)     __hip_atomic_load((p), __ATOMIC_RELAXED, __HIP_MEMORY_SCOPE_AGENT)
#define LLC_ST(p, v)  __hip_atomic_store((p), (v), __ATOMIC_RELAXED, __HIP_MEMORY_SCOPE_AGENT)

// ---------------------------------------------------------------------------
// Kernel A: gates_d[lt][g][b] = sum_e input_d[b][t0+lt][e] * W1[g][e] + b1[g]
// ---------------------------------------------------------------------------
__global__ __launch_bounds__(256) void k_gates_d(const float* __restrict__ xd,
                                                 const float* __restrict__ W1,
                                                 const float* __restrict__ b1,
                                                 float* __restrict__ gd, int t0) {
  __shared__ float As[16][132];
  __shared__ float Bs[16][68];
  const int lt  = blockIdx.x >> 5;
  const int tg  = t0 + lt;
  const int g0  = (blockIdx.x & 31) << 7;
  const int tid = threadIdx.x;
  const int tx  = tid & 15;
  const int ty  = tid >> 4;
  float acc[8][4];
#pragma unroll
  for (int i = 0; i < 8; ++i)
#pragma unroll
    for (int j = 0; j < 4; ++j) acc[i][j] = 0.f;

  const int lg  = tid >> 1;
  const int lk  = (tid & 1) << 3;
  const int lb  = tid >> 2;
  const int lbk = (tid & 3) << 2;

  for (int k0 = 0; k0 < E_; k0 += 16) {
    float4 w0 = *(const float4*)&W1[(size_t)(g0 + lg) * WLD_ + (k0 + lk)];
    float4 w1 = *(const float4*)&W1[(size_t)(g0 + lg) * WLD_ + (k0 + lk + 4)];
    float4 xv = *(const float4*)&xd[(size_t)lb * (T_ * E_) + (size_t)tg * E_ + (k0 + lbk)];
    As[lk + 0][lg] = w0.x; As[lk + 1][lg] = w0.y; As[lk + 2][lg] = w0.z; As[lk + 3][lg] = w0.w;
    As[lk + 4][lg] = w1.x; As[lk + 5][lg] = w1.y; As[lk + 6][lg] = w1.z; As[lk + 7][lg] = w1.w;
    Bs[lbk + 0][lb] = xv.x; Bs[lbk + 1][lb] = xv.y; Bs[lbk + 2][lb] = xv.z; Bs[lbk + 3][lb] = xv.w;
    __syncthreads();
#pragma unroll
    for (int k = 0; k < 16; ++k) {
      float4 a0 = *(const float4*)&As[k][ty << 3];
      float4 a1 = *(const float4*)&As[k][(ty << 3) + 4];
      float4 bv = *(const float4*)&Bs[k][tx << 2];
      float av[8] = {a0.x, a0.y, a0.z, a0.w, a1.x, a1.y, a1.z, a1.w};
#pragma unroll
      for (int i = 0; i < 8; ++i) {
        acc[i][0] = fmaf(av[i], bv.x, acc[i][0]);
        acc[i][1] = fmaf(av[i], bv.y, acc[i][1]);
        acc[i][2] = fmaf(av[i], bv.z, acc[i][2]);
        acc[i][3] = fmaf(av[i], bv.w, acc[i][3]);
      }
    }
    __syncthreads();
  }
#pragma unroll
  for (int i = 0; i < 8; ++i) {
    const int g = g0 + (ty << 3) + i;
    const float bias = b1[g];
    float4 st = make_float4(acc[i][0] + bias, acc[i][1] + bias,
                            acc[i][2] + bias, acc[i][3] + bias);
    *(float4*)&gd[((size_t)lt * G4_ + g) * B_ + (tx << 2)] = st;
  }
}

// ---------------------------------------------------------------------------
// Kernel B: field[lt][n][b] = sigmoid(lg)*tanh(zh) from input_z @ Wz^T + bz
// ---------------------------------------------------------------------------
__global__ __launch_bounds__(256) void k_field(const float* __restrict__ xz,
                                               const float* __restrict__ Wz,
                                               const float* __restrict__ bz,
                                               float* __restrict__ field, int t0) {
  __shared__ float Ls[32][68];
  __shared__ float Zs[32][68];
  __shared__ float Xs[32][68];
  const int lt  = blockIdx.x >> 4;
  const int tg  = t0 + lt;
  const int n0  = (blockIdx.x & 15) << 6;
  const int tid = threadIdx.x;
  const int tx  = tid & 15;
  const int ty  = tid >> 4;
  float aL[4][4], aZ[4][4];
#pragma unroll
  for (int i = 0; i < 4; ++i)
#pragma unroll
    for (int j = 0; j < 4; ++j) { aL[i][j] = 0.f; aZ[i][j] = 0.f; }

  const int ln = tid >> 2;
  const int lk = (tid & 3) << 3;

  for (int k0 = 0; k0 < Z_; k0 += 32) {
    float4 l0 = *(const float4*)&Wz[(size_t)(n0 + ln) * Z_ + k0 + lk];
    float4 l1 = *(const float4*)&Wz[(size_t)(n0 + ln) * Z_ + k0 + lk + 4];
    float4 z0 = *(const float4*)&Wz[(size_t)(H_ + n0 + ln) * Z_ + k0 + lk];
    float4 z1 = *(const float4*)&Wz[(size_t)(H_ + n0 + ln) * Z_ + k0 + lk + 4];
    float4 x0 = *(const float4*)&xz[(size_t)ln * (T_ * Z_) + (size_t)tg * Z_ + k0 + lk];
    float4 x1 = *(const float4*)&xz[(size_t)ln * (T_ * Z_) + (size_t)tg * Z_ + k0 + lk + 4];
    Ls[lk + 0][ln] = l0.x; Ls[lk + 1][ln] = l0.y; Ls[lk + 2][ln] = l0.z; Ls[lk + 3][ln] = l0.w;
    Ls[lk + 4][ln] = l1.x; Ls[lk + 5][ln] = l1.y; Ls[lk + 6][ln] = l1.z; Ls[lk + 7][ln] = l1.w;
    Zs[lk + 0][ln] = z0.x; Zs[lk + 1][ln] = z0.y; Zs[lk + 2][ln] = z0.z; Zs[lk + 3][ln] = z0.w;
    Zs[lk + 4][ln] = z1.x; Zs[lk + 5][ln] = z1.y; Zs[lk + 6][ln] = z1.z; Zs[lk + 7][ln] = z1.w;
    Xs[lk + 0][ln] = x0.x; Xs[lk + 1][ln] = x0.y; Xs[lk + 2][ln] = x0.z; Xs[lk + 3][ln] = x0.w;
    Xs[lk + 4][ln] = x1.x; Xs[lk + 5][ln] = x1.y; Xs[lk + 6][ln] = x1.z; Xs[lk + 7][ln] = x1.w;
    __syncthreads();
#pragma unroll
    for (int k = 0; k < 32; ++k) {
      float4 lv = *(const float4*)&Ls[k][ty << 2];
      float4 zv = *(const float4*)&Zs[k][ty << 2];
      float4 xv = *(const float4*)&Xs[k][tx << 2];
      float lvv[4] = {lv.x, lv.y, lv.z, lv.w};
      float zvv[4] = {zv.x, zv.y, zv.z, zv.w};
      float xvv[4] = {xv.x, xv.y, xv.z, xv.w};
#pragma unroll
      for (int i = 0; i < 4; ++i)
#pragma unroll
        for (int j = 0; j < 4; ++j) {
          aL[i][j] = fmaf(lvv[i], xvv[j], aL[i][j]);
          aZ[i][j] = fmaf(zvv[i], xvv[j], aZ[i][j]);
        }
    }
    __syncthreads();
  }
#pragma unroll
  for (int i = 0; i < 4; ++i) {
    const int nn = n0 + (ty << 2) + i;
    const float bL = bz[nn];
    const float bZ = bz[H_ + nn];
    float4 o;
    o.x = sigm_(aL[i][0] + bL) * tanh_(aZ[i][0] + bZ);
    o.y = sigm_(aL[i][1] + bL) * tanh_(aZ[i][1] + bZ);
    o.z = sigm_(aL[i][2] + bL) * tanh_(aZ[i][2] + bZ);
    o.w = sigm_(aL[i][3] + bL) * tanh_(aZ[i][3] + bZ);
    *(float4*)&field[((size_t)lt * H_ + nn) * B_ + (tx << 2)] = o;
  }
}

// ---------------------------------------------------------------------------
// Grouped fence-free barrier: 4 independent groups of 64 WGs (one per
// batch-group). slots[bg*64+cg]; aggregator = cg==0; roots padded to separate
// cachelines. All flag traffic LLC-direct relaxed atomics; caller must
// __syncthreads() (vmcnt drain) immediately before calling.
// ---------------------------------------------------------------------------
__device__ __forceinline__ void arrive_wait_grp(unsigned* __restrict__ slots,
                                                unsigned* __restrict__ roots,
                                                int bg, int cg, int tid,
                                                unsigned target) {
  if (tid == 0) LLC_ST(&slots[(bg << 6) + cg], target);
  if (cg == 0) {
    if (tid < 64) {
      while (LLC_LD(&slots[(bg << 6) + tid]) < target) __builtin_amdgcn_s_sleep(2);
    }
    __syncthreads();
    if (tid == 0) LLC_ST(&roots[bg << 5], target);
  } else {
    if (tid == 0) {
      while (LLC_LD(&roots[bg << 5]) < target) __builtin_amdgcn_s_sleep(2);
    }
    __syncthreads();
  }
}

// ---------------------------------------------------------------------------
// Kernel C: MFMA persistent scan. 256 WGs x 512 thr. WG(bg=wg>>6, cg=wg&63):
// 16 batches (bg) x 16 h-cols (n0=cg*16). Per step: GEMM (16b x 1024k) x
// (1024k x 64 gate-rows) via mfma_f32_16x16x32_bf16.
//   wave wv: gt = wv&3 (gate = N-tile), kh = wv>>2 (K-half, 16 K-tiles each).
//   Wh bf16 hi+lo resident in registers (B-frags); h staged in LDS per step.
//   K-half partials combine via LDS; kh==1 threads own the cell update
//   (c in registers), lane->(q = gt*4 + lane>>4, b = lane&15).
// Cross-WG h via parity-double-buffered hbuf (bf16), LLC-direct.
// ---------------------------------------------------------------------------
__global__ __launch_bounds__(512, 2) void k_rnn(const float* __restrict__ gd,
                                                const float* __restrict__ field,
                                                const float* __restrict__ hidden,
                                                const float* __restrict__ W1,
                                                float* __restrict__ out,
                                                ushort_t* __restrict__ hbuf,
                                                float* __restrict__ cbuf,
                                                unsigned* __restrict__ slots,
                                                unsigned* __restrict__ roots,
                                                int t0, unsigned gbase) {
  __shared__ __align__(16) unsigned char hlds[32768];  // h bf16 [16][1024], XOR-swizzled
  __shared__ __align__(16) float part[1024];           // [gt][lane][4] K-half partials
  __shared__ float gates_l[4 * 272];                   // [gt][b*17+q] (pad 17)
  __shared__ float hstage_f[256];                      // [b*16+q]
  __shared__ ushort_t hstage_b[256];

  const int wg   = blockIdx.x;
  const int tid  = threadIdx.x;
  const int lane = tid & 63;
  const int wv   = tid >> 6;
  const int gt   = wv & 3;       // N-tile (gate) for MFMA; q-block for update
  const int kh   = wv >> 2;      // K-half
  const int bg   = wg >> 6;
  const int cg   = wg & 63;
  const int n0   = cg << 4;

  // ---- Weight prologue: B-frags resident in registers (hi/lo bf16 split).
  // B[k][n] = Wh[gt*1024 + n0 + n][k]; lane = n + 16*kg holds k = kt*32+kg*8+j.
  const int nb = lane & 15;
  const int kg = lane >> 4;
  bf16x8 wh[16], wl[16];
  {
    const float* wrow = &W1[(size_t)((gt << 10) + n0 + nb) * WLD_ + E_ + (kh << 9) + (kg << 3)];
#pragma unroll
    for (int kt = 0; kt < 16; ++kt) {
      const float* p = wrow + (kt << 5);
      float4 v0 = *(const float4*)p;
      float4 v1 = *(const float4*)(p + 4);
      float v[8] = {v0.x, v0.y, v0.z, v0.w, v1.x, v1.y, v1.z, v1.w};
#pragma unroll
      for (int e = 0; e < 8; ++e) {
        ushort_t hi = f2bf(v[e]);
        ushort_t lo = f2bf(v[e] - bf2f(hi));
        wh[kt][e] = (short)hi;
        wl[kt][e] = (short)lo;
      }
    }
  }

  // ---- update-thread identity (kh==1 waves): 256 threads <-> (b,q)
  const int ub = lane & 15;
  const int uq = (gt << 2) + (lane >> 4);

  float c_st = 0.f, hlast = 0.f;
  unsigned* hbuf32 = (unsigned*)hbuf;

  if (t0 == 0) {
    if (kh == 1) {
      const float h0v = hidden[(size_t)((bg << 4) + ub) * (2 * H_) + n0 + uq];
      c_st = hidden[(size_t)((bg << 4) + ub) * (2 * H_) + H_ + n0 + uq];
      hstage_b[(ub << 4) + uq] = f2bf(h0v);
    }
    __syncthreads();
    if (tid < 128) {  // pack to hbuf parity 0 (coalesced 4B)
      const int b3 = tid >> 3, d = tid & 7;
      unsigned v = (unsigned)hstage_b[(b3 << 4) + (d << 1)]
                 | ((unsigned)hstage_b[(b3 << 4) + (d << 1) + 1] << 16);
      LLC_ST(&hbuf32[(((bg << 4) + b3) << 9) + (n0 >> 1) + d], v);
    }
  } else {
    if (kh == 1)
      c_st = LLC_LD(&cbuf[(size_t)((bg << 4) + ub) * H_ + n0 + uq]);
  }
  __syncthreads();  // drain hbuf stores (vmcnt 0) before arrival
  arrive_wait_grp(slots, roots, bg, cg, tid, gbase + 1);

  // per-lane A-frag base: row = lane&15 (local b), kg-column group
  const int abase = ((lane & 15) << 11) + (kh << 10) + (kg << 4);
  const int aswz  = ((lane & 15) & 7) << 4;
  // staging addressing (all 512 threads, 64B each, coalesced both sides)
  const int sb  = tid >> 5;         // local b row 0..15
  const int st32 = tid & 31;
  const int sswz = (sb & 7) << 4;

  for (int lt = 0; lt < TC_; ++lt) {
    // -- early gd/field loads (update threads only; latency hides under GEMM)
    float gdv[4], fldv = 0.f;
    if (kh == 1) {
#pragma unroll
      for (int g = 0; g < 4; ++g)
        gdv[g] = gd[((size_t)lt * G4_ + (g << 10) + n0 + uq) * B_ + (bg << 4) + ub];
      fldv = field[((size_t)lt * H_ + n0 + uq) * B_ + (bg << 4) + ub];
    }

    // -- stage h chunk: hbuf[parity] -> LDS (bf16, swizzled)
    {
      const ull_t* hb64 = (const ull_t*)hbuf + (size_t)((t0 + lt) & 1) * 16384;
      const ull_t* src = hb64 + ((((bg << 4) + sb) << 8));
#pragma unroll
      for (int m = 0; m < 8; ++m) {
        ull_t v = LLC_LD(src + st32 + (m << 5));
        const int wo = (sb << 11) + (st32 << 3) + (m << 8);
        *(ull_t*)(hlds + (wo ^ sswz)) = v;
      }
    }
    __syncthreads();

    // -- MFMA: 16 K-tiles x 2 passes (w_hi, w_lo)
    f32x4 accH = {0.f, 0.f, 0.f, 0.f};
    f32x4 accL = {0.f, 0.f, 0.f, 0.f};
#pragma unroll
    for (int kt = 0; kt < 16; ++kt) {
      bf16x8 av = *(const bf16x8*)(hlds + ((abase + (kt << 6)) ^ aswz));
      accH = __builtin_amdgcn_mfma_f32_16x16x32_bf16(av, wh[kt], accH, 0, 0, 0);
      accL = __builtin_amdgcn_mfma_f32_16x16x32_bf16(av, wl[kt], accL, 0, 0, 0);
    }
    f32x4 acc = accH + accL;

    // -- K-half combine via LDS
    if (kh == 1) *(f32x4*)&part[(gt << 8) + (lane << 2)] = acc;
    __syncthreads();
    if (kh == 0) {
      f32x4 p = *(const f32x4*)&part[(gt << 8) + (lane << 2)];
      acc += p;
      // C/D layout: col n = lane&15, row m = (lane>>4)*4 + r  -> gates_l[gt][m*17+n]
#pragma unroll
      for (int r = 0; r < 4; ++r)
        gates_l[gt * 272 + (((lane >> 4) << 2) + r) * 17 + (lane & 15)] = acc[r];
    }
    __syncthreads();

    // -- cell update (kh==1 threads: one (b,q) each; c in registers)
    if (kh == 1) {
      const float gi = gates_l[0 * 272 + ub * 17 + uq] + gdv[0];
      const float gf = gates_l[1 * 272 + ub * 17 + uq] + gdv[1];
      const float gg = gates_l[2 * 272 + ub * 17 + uq] + gdv[2];
      const float go = gates_l[3 * 272 + ub * 17 + uq] + gdv[3];
      c_st  = sigm_(gf + 1.f) * c_st + sigm_(gi) * tanh_(gg) + fldv;
      hlast = sigm_(go) * tanh_(c_st);
      hstage_f[(ub << 4) + uq] = hlast;
      hstage_b[(ub << 4) + uq] = f2bf(hlast);
    }
    __syncthreads();

    // -- publish: out (f32, coalesced) + hbuf[parity^1] (bf16 packed, LLC)
    if (tid < 256) {
      const int b2 = tid >> 4, q2 = tid & 15;
      out[((size_t)((bg << 4) + b2) * T_ + (t0 + lt)) * H_ + n0 + q2] = hstage_f[tid];
    }
    if (tid < 128) {
      const int b3 = tid >> 3, d = tid & 7;
      unsigned v = (unsigned)hstage_b[(b3 << 4) + (d << 1)]
                 | ((unsigned)hstage_b[(b3 << 4) + (d << 1) + 1] << 16);
      LLC_ST(&hbuf32[(size_t)(((t0 + lt + 1) & 1)) * 32768
                     + (((bg << 4) + b3) << 9) + (n0 >> 1) + d], v);
    }
    __syncthreads();  // drain hbuf/out stores before arrival
    arrive_wait_grp(slots, roots, bg, cg, tid, gbase + 2 + (unsigned)lt);
  }

  // ---- chunk epilogue: persist c; final h_f/c_f on last chunk
  if (kh == 1) {
    LLC_ST(&cbuf[(size_t)((bg << 4) + ub) * H_ + n0 + uq], c_st);
    if (t0 == T_ - TC_) {
      out[(size_t)B_ * T_ * H_ + (size_t)((bg << 4) + ub) * H_ + n0 + uq] = hlast;
      out[(size_t)B_ * T_ * H_ + (size_t)B_ * H_ + (size_t)((bg << 4) + ub) * H_ + n0 + uq] = c_st;
    }
  }
}

// ---------------------------------------------------------------------------
extern "C" void kernel_launch(void* const* d_in, const int* in_sizes, int n_in,
                              void* d_out, int out_size, void* d_ws, size_t ws_size,
                              hipStream_t stream) {
  const float* xd     = (const float*)d_in[0];
  const float* xz     = (const float*)d_in[1];
  const float* hidden = (const float*)d_in[2];
  const float* W1     = (const float*)d_in[3];
  const float* b1     = (const float*)d_in[4];
  const float* Wz     = (const float*)d_in[5];
  const float* bz     = (const float*)d_in[6];
  float* out = (float*)d_out;
  float* ws  = (float*)d_ws;

  // ws layout (floats): gd chunk 33554432 | field chunk 8388608 |
  //   hbuf 2x64x1024 bf16 (=65536 f32) | cbuf 65536 | slots 256 | roots 128
  float* gd    = ws;
  float* field = gd + (size_t)TC_ * G4_ * B_;
  ushort_t* hbuf = (ushort_t*)(field + (size_t)TC_ * H_ * B_);
  float* cbuf  = (float*)(hbuf + 2 * 64 * 1024);
  unsigned* slots = (unsigned*)(cbuf + (size_t)B_ * H_);
  unsigned* roots = slots + 256;

  hipMemsetAsync(slots, 0, (256 + 128) * sizeof(unsigned), stream);
  for (int c = 0; c < NCH_; ++c) {
    const int t0 = c * TC_;
    const unsigned gbase = (unsigned)c * 130u;
    k_gates_d<<<dim3(TC_ * 32), dim3(256), 0, stream>>>(xd, W1, b1, gd, t0);
    k_field<<<dim3(TC_ * 16), dim3(256), 0, stream>>>(xz, Wz, bz, field, t0);
    k_rnn<<<dim3(NWG_), dim3(512), 0, stream>>>(gd, field, hidden, W1, out,
                                                hbuf, cbuf, slots, roots, t0, gbase);
  }
}